// Round 16
// baseline (274.570 us; speedup 1.0000x reference)
//
#include <hip/hip_runtime.h>
#include <hip/hip_bf16.h>

typedef __hip_bfloat16 bf16;
typedef __attribute__((ext_vector_type(8))) short short8v;
typedef __attribute__((ext_vector_type(4))) short short4v;
typedef __attribute__((ext_vector_type(4))) float f32x4;
typedef __attribute__((ext_vector_type(16))) float f32x16;
typedef __attribute__((ext_vector_type(4))) unsigned int uint4v;
typedef unsigned int u32;

#define MFMA_16x16x32(a, b, c) __builtin_amdgcn_mfma_f32_16x16x32_bf16((a), (b), (c), 0, 0, 0)
#define MFMA_32x32x16(a, b, c) __builtin_amdgcn_mfma_f32_32x32x16_bf16((a), (b), (c), 0, 0, 0)

constexpr int Bc = 2, Sc = 2048, DMc = 2048, Hc = 16, DLc = 512, DHc = 128;

__device__ __forceinline__ void gload_lds16(const bf16* g, void* lds) {
  __builtin_amdgcn_global_load_lds(
      (const __attribute__((address_space(1))) void*)g,
      (__attribute__((address_space(3))) void*)lds, 16, 0, 0);
}

__device__ __forceinline__ unsigned short bf16bits(float f) {
  return __builtin_bit_cast(unsigned short, __float2bfloat16(f));
}

// ---------------------------------------------------------------------------
// fp32 -> bf16 conversion over 6 segments, one launch
// ---------------------------------------------------------------------------
struct CvtArgs {
  const float* src[6];
  bf16* dst[6];
  unsigned int cum[6];
  unsigned int total4;
};

__global__ __launch_bounds__(256) void cvt_all_kernel(CvtArgs a)
{
  unsigned int i = blockIdx.x * 256 + threadIdx.x;
  const unsigned int stride = gridDim.x * 256;
  for (; i < a.total4; i += stride) {
    int s = 0;
#pragma unroll
    for (int k = 1; k < 6; ++k) s += (i >= a.cum[k]) ? 1 : 0;
    unsigned int off = (i - a.cum[s]) * 4;
    float4 v = *(const float4*)(a.src[s] + off);
    short4v p;
    p[0] = (short)bf16bits(v.x);
    p[1] = (short)bf16bits(v.y);
    p[2] = (short)bf16bits(v.z);
    p[3] = (short)bf16bits(v.w);
    *(short4v*)(a.dst[s] + off) = p;
  }
}

// ---------------------------------------------------------------------------
// 8-phase 256x256 GEMM tile (T3+T4), BK=64, 8 waves (2M x 4N), per-wave
// 128x64 output. LDS: per operand 2 dbuf x 2 half x [2 kk][128 rows][64 B]
// = 64 KB (A) + 64 KB (B). Stage unit = (half,kk) = 8 KB = 1 global_load_lds
// issue by 512 threads. Swizzle: colB ^= ((row>>1)&3)<<4 (issue-invariant;
// same involution on read). Counted vmcnt: phases 1/3 wait vmcnt(4) -> the
// 4 oldest (this tile's k-half units) drain, the next 4 stay in flight
// across the barrier. Issues of tile kt+1 spread 2/phase in consumption
// order A-k0, B-k0, A-k1, B-k1. Last tile peeled (no issues, ph3 vmcnt(0)).
// EPI: 0 bf16 C, 1 bf16 C^T, 2 fp32 C.
// ---------------------------------------------------------------------------
#define GPHASE(bufv, KK, MH)                                                \
  do {                                                                      \
    const char* ap_ = aR + (bufv) * 32768 + (KK) * 8192 + (MH) * 4096;      \
    const char* bp_ = bR + (bufv) * 32768 + (KK) * 8192;                    \
    short8v af_[4], bf_[4];                                                 \
    _Pragma("unroll")                                                       \
    for (int m4 = 0; m4 < 4; ++m4)                                          \
      af_[m4] = *(const short8v*)(ap_ + m4 * 1024);                         \
    _Pragma("unroll")                                                       \
    for (int n = 0; n < 4; ++n)                                             \
      bf_[n] = *(const short8v*)(bp_ + n * 1024);                           \
    __builtin_amdgcn_s_setprio(1);                                          \
    _Pragma("unroll")                                                       \
    for (int m4 = 0; m4 < 4; ++m4)                                          \
      _Pragma("unroll")                                                     \
      for (int n = 0; n < 4; ++n)                                           \
        acc[(MH) * 4 + m4][n] =                                             \
            MFMA_16x16x32(af_[m4], bf_[n], acc[(MH) * 4 + m4][n]);          \
    __builtin_amdgcn_s_setprio(0);                                          \
  } while (0)

template<int EPI>
__device__ __forceinline__ void gemm_tile_256(
    const bf16* __restrict__ A, const bf16* __restrict__ BT, void* __restrict__ Cv,
    int K, int ldc, int row0, int col0, char* AsC, char* BsC)
{
  const int tid = threadIdx.x;
  const int lane = tid & 63, wid = tid >> 6;
  const int wm = wid >> 2, wn = wid & 3;
  const int fr = lane & 15, g = lane >> 4;

  f32x4 acc[8][4] = {};

  // staging: thread covers row = tid>>2 (0..127) of a unit, colB = (tid&3)*16
  const int srow = tid >> 2;
  const int scolS = ((tid & 3) * 16) ^ (((srow >> 1) & 3) << 4);
  const bf16* sA = A + (size_t)(row0 + srow) * K + (scolS >> 1);
  const bf16* sB = BT + (size_t)(col0 + srow) * K + (scolS >> 1);
  char* AsW = AsC + wid * 1024;
  char* BsW = BsC + wid * 1024;

  auto ISSA = [&](int buf, int h, int kk, int kt) {
    gload_lds16(sA + (size_t)(h * 128) * K + kt * 64 + kk * 32,
                AsW + buf * 32768 + h * 16384 + kk * 8192);
  };
  auto ISSB = [&](int buf, int h, int kk, int kt) {
    gload_lds16(sB + (size_t)(h * 128) * K + kt * 64 + kk * 32,
                BsW + buf * 32768 + h * 16384 + kk * 8192);
  };

  // read bases (lane consts); phase adds buf/kk/mh/m-offsets
  const int rdLane = fr * 64 + ((g * 16) ^ (((fr >> 1) & 3) << 4));
  const char* aR = AsC + wm * 16384 + rdLane;
  const char* bR = BsC + (wn >> 1) * 16384 + (wn & 1) * 4096 + rdLane;

  // prologue: tile 0 fully staged (k0 group first, then k1 group)
  ISSA(0, 0, 0, 0); ISSA(0, 1, 0, 0); ISSB(0, 0, 0, 0); ISSB(0, 1, 0, 0);
  ISSA(0, 0, 1, 0); ISSA(0, 1, 1, 0); ISSB(0, 0, 1, 0); ISSB(0, 1, 1, 0);

  const int KT = K >> 6;
  for (int kt = 0; kt < KT - 1; ++kt) {
    const int buf = kt & 1, nb = buf ^ 1;
    asm volatile("s_waitcnt vmcnt(4)" ::: "memory");
    __builtin_amdgcn_s_barrier();
    asm volatile("" ::: "memory");
    ISSA(nb, 0, 0, kt + 1); ISSA(nb, 1, 0, kt + 1);
    GPHASE(buf, 0, 0);
    ISSB(nb, 0, 0, kt + 1); ISSB(nb, 1, 0, kt + 1);
    GPHASE(buf, 0, 1);
    asm volatile("s_waitcnt vmcnt(4)" ::: "memory");
    __builtin_amdgcn_s_barrier();
    asm volatile("" ::: "memory");
    ISSA(nb, 0, 1, kt + 1); ISSA(nb, 1, 1, kt + 1);
    GPHASE(buf, 1, 0);
    ISSB(nb, 0, 1, kt + 1); ISSB(nb, 1, 1, kt + 1);
    GPHASE(buf, 1, 1);
  }
  {
    const int buf = (KT - 1) & 1;
    asm volatile("s_waitcnt vmcnt(4)" ::: "memory");
    __builtin_amdgcn_s_barrier();
    asm volatile("" ::: "memory");
    GPHASE(buf, 0, 0);
    GPHASE(buf, 0, 1);
    asm volatile("s_waitcnt vmcnt(0)" ::: "memory");
    __builtin_amdgcn_s_barrier();
    asm volatile("" ::: "memory");
    GPHASE(buf, 1, 0);
    GPHASE(buf, 1, 1);
  }

  // epilogue
  const int crow = g * 4, ccol = fr;
  if (EPI == 0) {
    bf16* C = (bf16*)Cv;
#pragma unroll
    for (int m = 0; m < 8; ++m)
#pragma unroll
      for (int n = 0; n < 4; ++n) {
        bf16* Cp = C + (size_t)(row0 + wm * 128 + m * 16 + crow) * ldc
                     + col0 + wn * 64 + n * 16 + ccol;
#pragma unroll
        for (int r = 0; r < 4; ++r)
          Cp[(size_t)r * ldc] = __float2bfloat16(acc[m][n][r]);
      }
  } else if (EPI == 1) {
    bf16* C = (bf16*)Cv;
#pragma unroll
    for (int m = 0; m < 8; ++m)
#pragma unroll
      for (int n = 0; n < 4; ++n) {
        short4v pk;
#pragma unroll
        for (int r = 0; r < 4; ++r)
          pk[r] = (short)bf16bits(acc[m][n][r]);
        bf16* Cp = C + (size_t)(col0 + wn * 64 + n * 16 + ccol) * ldc
                     + row0 + wm * 128 + m * 16 + crow;
        *(short4v*)Cp = pk;
      }
  } else {
    float* C = (float*)Cv;
#pragma unroll
    for (int m = 0; m < 8; ++m)
#pragma unroll
      for (int n = 0; n < 4; ++n) {
        float* Cp = C + (size_t)(row0 + wm * 128 + m * 16 + crow) * ldc
                      + col0 + wn * 64 + n * 16 + ccol;
#pragma unroll
        for (int r = 0; r < 4; ++r)
          Cp[(size_t)r * ldc] = acc[m][n][r];
      }
  }
}

// Fused Q-proj + KV-down: grid (10,16); bx<8 -> Qb, else Ck.
__global__ __launch_bounds__(512, 2) void qkv_gemm_kernel(
    const bf16* __restrict__ xb, const bf16* __restrict__ Wqb,
    const bf16* __restrict__ Wdkvb, bf16* __restrict__ Qb, bf16* __restrict__ Ck)
{
  __shared__ char As[65536];
  __shared__ char Bs[65536];
  const int flat = blockIdx.x + 10 * blockIdx.y;
  const int role = (flat & 7) * 20 + (flat >> 3);
  const int bx = role % 10, by = role / 10;
  if (bx < 8)
    gemm_tile_256<0>(xb, Wqb, Qb, DMc, DMc, by * 256, bx * 256, As, Bs);
  else
    gemm_tile_256<0>(xb, Wdkvb, Ck, DMc, DLc, by * 256, (bx - 8) * 256, As, Bs);
}

// Fused K-up + V-up: grid (16,16); bx<8 -> Kcat (row-major), else VTcat (C^T).
__global__ __launch_bounds__(512, 2) void up_gemm_kernel(
    const bf16* __restrict__ Ck, const bf16* __restrict__ Wukb,
    const bf16* __restrict__ Wuvb, bf16* __restrict__ Kcat, bf16* __restrict__ VTcat)
{
  __shared__ char As[65536];
  __shared__ char Bs[65536];
  const int flat = blockIdx.x + 16 * blockIdx.y;
  const int role = (flat & 7) * 32 + (flat >> 3);
  const int bx = role & 15, by = role >> 4;
  if (bx < 8)
    gemm_tile_256<0>(Ck, Wukb, Kcat, DLc, DMc, by * 256, bx * 256, As, Bs);
  else
    gemm_tile_256<1>(Ck, Wuvb, VTcat, DLc, Bc * Sc, by * 256, (bx - 8) * 256, As, Bs);
}

// Out-projection: grid (8,16), fp32 C.
__global__ __launch_bounds__(512, 2) void out_gemm_kernel(
    const bf16* __restrict__ AO, const bf16* __restrict__ Wob, float* __restrict__ out)
{
  __shared__ char As[65536];
  __shared__ char Bs[65536];
  const int flat = blockIdx.x + 8 * blockIdx.y;
  const int role = (flat & 7) * 16 + (flat >> 3);
  const int bx = role & 7, by = role >> 3;
  gemm_tile_256<2>(AO, Wob, out, DMc, DMc, by * 256, bx * 256, As, Bs);
}

// ---------------------------------------------------------------------------
// Flash attention (r15-verified): 32x32x16 swapped-operand MFMA, in-register
// softmax, cvt_pk/permlane32 P conversion; 4-wave blocks, 2 blocks/CU.
// ---------------------------------------------------------------------------
constexpr int KVB = 64;
constexpr int NTT = Sc / KVB;   // 32 tiles
constexpr int VSTR = Bc * Sc;   // 4096

__global__ __launch_bounds__(256, 2) void mla_attn_kernel(
    const bf16* __restrict__ Q, const bf16* __restrict__ Kcat,
    const bf16* __restrict__ VTcat, bf16* __restrict__ O)
{
  __shared__ bf16 Ks[2][KVB * 128];    // 16 KB each ([64][256B])
  __shared__ bf16 Vs[2][64 * 128];     // 16 KB each ([64][256B], d-pairs)

  const int tid = threadIdx.x, lane = tid & 63, wid = tid >> 6;  // wid 0..3
  const int l31 = lane & 31, hi = lane >> 5;

  // XCD role remap: grid (16,16,2) = 512 blocks; each XCD serves 4 heads.
  const int flat = blockIdx.x + 16 * (blockIdx.y + 16 * blockIdx.z);
  const int role = (flat & 7) * 64 + (flat >> 3);
  const int qb = role & 15, h = (role >> 4) & 15, b = role >> 8;
  const int q0 = qb * 128 + wid * 32;

  const bf16* Qp = Q + (size_t)(b * Sc + q0 + l31) * DMc + h * DHc + hi * 8;
  short8v qf[8];
#pragma unroll
  for (int kk = 0; kk < 8; ++kk) qf[kk] = *(const short8v*)(Qp + kk * 16);

  const bf16* Kb = Kcat + (size_t)b * Sc * DMc + h * DHc;      // K[t][d], stride DMc
  const bf16* Vb = VTcat + (size_t)(h * DHc) * VSTR + b * Sc;  // VT[d][t], stride VSTR

  const int srow = wid * 4 + (lane >> 4);          // 0..15
  const int scolB = (lane & 15) * 16;
  const int swzK0 = ((srow & 7) << 4) ^ (((srow >> 3) & 1) << 6);
  const bf16* kpE = Kb + (size_t)srow * DMc + (((scolB ^ swzK0) & 255) >> 1);
  const bf16* kpO = Kb + (size_t)srow * DMc + ((((scolB ^ swzK0) ^ 128) & 255) >> 1);
  const int swzV0 = ((srow & 7) << 4) ^ (((srow >> 3) & 1) << 7);
  const int vcp = scolB ^ swzV0;
  const bf16* vp = Vb + (size_t)(2 * srow + (vcp >> 7)) * VSTR + ((vcp & 127) >> 1);

  auto STAGE = [&](int buf, int t0) {
    char* kd = (char*)(&Ks[buf][0]) + wid * 1024;
    gload_lds16(kpE + (size_t)t0 * DMc, kd);
    gload_lds16(kpO + (size_t)(t0 + 16) * DMc, kd + 4096);
    gload_lds16(kpE + (size_t)(t0 + 32) * DMc, kd + 8192);
    gload_lds16(kpO + (size_t)(t0 + 48) * DMc, kd + 12288);
    char* vd = (char*)(&Vs[buf][0]) + wid * 1024;
    const bf16* v0 = vp + t0;
    gload_lds16(v0, vd);
    gload_lds16(v0 + (size_t)32 * VSTR, vd + 4096);
    gload_lds16(v0 + (size_t)64 * VSTR, vd + 8192);
    gload_lds16(v0 + (size_t)96 * VSTR, vd + 12288);
  };

  const int swzR = ((l31 & 7) << 4) ^ (((l31 >> 3) & 1) << 6) ^ (((l31 >> 4) & 1) << 7);
  const int swzVR = (((l31 >> 1) & 7) << 4) ^ (((l31 >> 4) & 1) << 7);

  f32x16 oacc[4] = {};
  float m_r = -1e30f, l_r = 0.f, msc = 0.f;
  const float SCL2 = 0.12751650f;     // (1/sqrt(128)) * log2(e)
  const float THRraw = 47.0f;         // ~6 / SCL2 -> p bounded by 2^6

  STAGE(0, 0);
  int cur = 0;

  for (int it = 0; it < NTT; ++it) {
    asm volatile("s_waitcnt vmcnt(0)" ::: "memory");
    __builtin_amdgcn_s_barrier();
    asm volatile("" ::: "memory");
    if (it + 1 < NTT) STAGE(cur ^ 1, (it + 1) * KVB);
    asm volatile("" ::: "memory");

    f32x16 s0 = {}, s1 = {};
    const char* Kc = (const char*)(&Ks[cur][0]);
    __builtin_amdgcn_s_setprio(1);
#pragma unroll
    for (int kk = 0; kk < 8; ++kk) {
      const int cb = (kk * 32 + hi * 16) ^ swzR;
      short8v k0 = *(const short8v*)(Kc + l31 * 256 + cb);
      short8v k1 = *(const short8v*)(Kc + (32 + l31) * 256 + cb);
      s0 = MFMA_32x32x16(k0, qf[kk], s0);
      s1 = MFMA_32x32x16(k1, qf[kk], s1);
    }
    __builtin_amdgcn_s_setprio(0);

    float pm = s0[0];
#pragma unroll
    for (int i = 1; i < 16; ++i) pm = fmaxf(pm, s0[i]);
#pragma unroll
    for (int i = 0; i < 16; ++i) pm = fmaxf(pm, s1[i]);

    if (!__all(pm - m_r <= THRraw)) {
      float red = fmaxf(pm, __shfl_xor(pm, 32, 64));
      float mnew = fmaxf(m_r, red);
      float c = exp2f((m_r - mnew) * SCL2);
      m_r = mnew;
      msc = mnew * SCL2;
      l_r *= c;
#pragma unroll
      for (int db = 0; db < 4; ++db) oacc[db] *= c;
    }

    short8v pf[4];
#pragma unroll
    for (int tt = 0; tt < 2; ++tt) {
      const f32x16& s = tt ? s1 : s0;
#pragma unroll
      for (int half = 0; half < 2; ++half) {
        float e0 = exp2f(__builtin_fmaf(s[half * 8 + 0], SCL2, -msc));
        float e1 = exp2f(__builtin_fmaf(s[half * 8 + 1], SCL2, -msc));
        float e2 = exp2f(__builtin_fmaf(s[half * 8 + 2], SCL2, -msc));
        float e3 = exp2f(__builtin_fmaf(s[half * 8 + 3], SCL2, -msc));
        float e4 = exp2f(__builtin_fmaf(s[half * 8 + 4], SCL2, -msc));
        float e5 = exp2f(__builtin_fmaf(s[half * 8 + 5], SCL2, -msc));
        float e6 = exp2f(__builtin_fmaf(s[half * 8 + 6], SCL2, -msc));
        float e7 = exp2f(__builtin_fmaf(s[half * 8 + 7], SCL2, -msc));
        l_r += ((e0 + e1) + (e2 + e3)) + ((e4 + e5) + (e6 + e7));
        u32 cA, cB, cC, cD;
        asm("v_cvt_pk_bf16_f32 %0, %1, %2" : "=v"(cA) : "v"(e0), "v"(e1));
        asm("v_cvt_pk_bf16_f32 %0, %1, %2" : "=v"(cB) : "v"(e2), "v"(e3));
        asm("v_cvt_pk_bf16_f32 %0, %1, %2" : "=v"(cC) : "v"(e4), "v"(e5));
        asm("v_cvt_pk_bf16_f32 %0, %1, %2" : "=v"(cD) : "v"(e6), "v"(e7));
        asm volatile("v_permlane32_swap_b32 %0, %1" : "+v"(cA), "+v"(cC));
        asm volatile("v_permlane32_swap_b32 %0, %1" : "+v"(cB), "+v"(cD));
        uint4v w;
        w[0] = cA; w[1] = cB; w[2] = cC; w[3] = cD;
        pf[tt * 2 + half] = __builtin_bit_cast(short8v, w);
      }
    }

    const char* Vc = (const char*)(&Vs[cur][0]);
    __builtin_amdgcn_s_setprio(1);
#pragma unroll
    for (int db = 0; db < 4; ++db) {
      const int vrow = (db * 16 + (l31 >> 1)) * 256;
#pragma unroll
      for (int ts = 0; ts < 4; ++ts) {
        const int cb = ((l31 & 1) * 128 + ts * 32 + hi * 16) ^ swzVR;
        short8v vf = *(const short8v*)(Vc + vrow + cb);
        oacc[db] = MFMA_32x32x16(vf, pf[ts], oacc[db]);
      }
    }
    __builtin_amdgcn_s_setprio(0);

    cur ^= 1;
  }

  float l = l_r + __shfl_xor(l_r, 32, 64);
  float inv = 1.f / l;
  bf16* Op = O + (size_t)(b * Sc + q0 + l31) * DMc + h * DHc + hi * 4;
#pragma unroll
  for (int db = 0; db < 4; ++db) {
#pragma unroll
    for (int rq = 0; rq < 4; ++rq) {
      short4v pk;
#pragma unroll
      for (int r = 0; r < 4; ++r)
        pk[r] = (short)bf16bits(oacc[db][rq * 4 + r] * inv);
      *(short4v*)(Op + db * 32 + rq * 8) = pk;
    }
  }
}

// ---------------------------------------------------------------------------
extern "C" void kernel_launch(void* const* d_in, const int* in_sizes, int n_in,
                              void* d_out, int out_size, void* d_ws, size_t ws_size,
                              hipStream_t stream)
{
  const float* x    = (const float*)d_in[0];
  const float* Wq   = (const float*)d_in[1];
  const float* Wdkv = (const float*)d_in[2];
  const float* Wuk  = (const float*)d_in[3];
  const float* Wuv  = (const float*)d_in[4];
  const float* Wo   = (const float*)d_in[5];
  float* out = (float*)d_out;

  char* ws = (char*)d_ws;
  bf16* Qb    = (bf16*)(ws + 0);              // 16 MB
  bf16* Kcat  = (bf16*)(ws + 16777216);       // 16 MB  (B*S, H*DH)
  bf16* VTcat = (bf16*)(ws + 33554432);       // 16 MB  (H*DH, B*S)
  bf16* xb    = (bf16*)(ws + 50331648);       // 16 MB (dead after qkv gemm)
  bf16* AO    = (bf16*)(ws + 50331648);       // overlay: attn output
  bf16* Ck    = (bf16*)(ws + 67108864);       //  4 MB
  bf16* Wqb   = (bf16*)(ws + 71303168);       //  8 MB
  bf16* Wdkvb = (bf16*)(ws + 79691776);       //  2 MB
  bf16* Wukb  = (bf16*)(ws + 81788928);       //  2 MB
  bf16* Wuvb  = (bf16*)(ws + 83886080);       //  2 MB
  bf16* Wob   = (bf16*)(ws + 85983232);       //  8 MB

  dim3 blk(256, 1, 1);

  CvtArgs ca;
  ca.src[0] = x;    ca.dst[0] = xb;
  ca.src[1] = Wq;   ca.dst[1] = Wqb;
  ca.src[2] = Wdkv; ca.dst[2] = Wdkvb;
  ca.src[3] = Wuk;  ca.dst[3] = Wukb;
  ca.src[4] = Wuv;  ca.dst[4] = Wuvb;
  ca.src[5] = Wo;   ca.dst[5] = Wob;
  unsigned int n4[6] = { (unsigned)(Bc * Sc * DMc / 4), (unsigned)(DMc * DMc / 4),
                         (unsigned)(DLc * DMc / 4),     (unsigned)(Hc * DHc * DLc / 4),
                         (unsigned)(Hc * DHc * DLc / 4),(unsigned)(DMc * DMc / 4) };
  unsigned int acc = 0;
  for (int i = 0; i < 6; ++i) { ca.cum[i] = acc; acc += n4[i]; }
  ca.total4 = acc;
  cvt_all_kernel<<<2048, blk, 0, stream>>>(ca);

  // Q = x@Wq^T and Ckv = x@Wdkv^T (256-tile, 8-phase)
  qkv_gemm_kernel<<<dim3(10, 16), dim3(512, 1, 1), 0, stream>>>(xb, Wqb, Wdkvb, Qb, Ck);

  // K/V up-projections (256-tile, 8-phase)
  up_gemm_kernel<<<dim3(16, 16), dim3(512, 1, 1), 0, stream>>>(Ck, Wukb, Wuvb, Kcat, VTcat);

  // attention: 4-wave blocks, 2 blocks/CU
  mla_attn_kernel<<<dim3(Sc / 128, Hc, Bc), dim3(256, 1, 1), 0, stream>>>(
      Qb, Kcat, VTcat, AO);

  // out = AO @ Wo^T (fp32 out, 256-tile, 8-phase)
  out_gemm_kernel<<<dim3(8, 16), dim3(512, 1, 1), 0, stream>>>(AO, Wob, out);
}

// Round 17
// 235.064 us; speedup vs baseline: 1.1681x; 1.1681x over previous
//
#include <hip/hip_runtime.h>
#include <hip/hip_bf16.h>

typedef __hip_bfloat16 bf16;
typedef __attribute__((ext_vector_type(8))) short short8v;
typedef __attribute__((ext_vector_type(4))) short short4v;
typedef __attribute__((ext_vector_type(4))) float f32x4;
typedef __attribute__((ext_vector_type(16))) float f32x16;
typedef __attribute__((ext_vector_type(4))) unsigned int uint4v;
typedef unsigned int u32;

#define MFMA_16x16x32(a, b, c) __builtin_amdgcn_mfma_f32_16x16x32_bf16((a), (b), (c), 0, 0, 0)
#define MFMA_32x32x16(a, b, c) __builtin_amdgcn_mfma_f32_32x32x16_bf16((a), (b), (c), 0, 0, 0)

constexpr int Bc = 2, Sc = 2048, DMc = 2048, Hc = 16, DLc = 512, DHc = 128;

__device__ __forceinline__ void gload_lds16(const bf16* g, void* lds) {
  __builtin_amdgcn_global_load_lds(
      (const __attribute__((address_space(1))) void*)g,
      (__attribute__((address_space(3))) void*)lds, 16, 0, 0);
}

__device__ __forceinline__ unsigned short bf16bits(float f) {
  return __builtin_bit_cast(unsigned short, __float2bfloat16(f));
}

// ---------------------------------------------------------------------------
// fp32 -> bf16 conversion over 6 segments, one launch
// ---------------------------------------------------------------------------
struct CvtArgs {
  const float* src[6];
  bf16* dst[6];
  unsigned int cum[6];
  unsigned int total4;
};

__global__ __launch_bounds__(256) void cvt_all_kernel(CvtArgs a)
{
  unsigned int i = blockIdx.x * 256 + threadIdx.x;
  const unsigned int stride = gridDim.x * 256;
  for (; i < a.total4; i += stride) {
    int s = 0;
#pragma unroll
    for (int k = 1; k < 6; ++k) s += (i >= a.cum[k]) ? 1 : 0;
    unsigned int off = (i - a.cum[s]) * 4;
    float4 v = *(const float4*)(a.src[s] + off);
    short4v p;
    p[0] = (short)bf16bits(v.x);
    p[1] = (short)bf16bits(v.y);
    p[2] = (short)bf16bits(v.z);
    p[3] = (short)bf16bits(v.w);
    *(short4v*)(a.dst[s] + off) = p;
  }
}

// ---------------------------------------------------------------------------
// 128x128 tile GEMM (r15-verified m97 structure), BK=32.
// EPI: 0 bf16 C, 1 bf16 C^T, 2 fp32 C.
// ---------------------------------------------------------------------------
template<int EPI>
__device__ __forceinline__ void gemm_tile_128(
    const bf16* __restrict__ A, const bf16* __restrict__ BT, void* __restrict__ Cv,
    int K, int ldc, int row0, int col0, bf16* As, bf16* Bs)
{
  const int tid = threadIdx.x;
  const int lane = tid & 63, wid = tid >> 6;
  const int wr = wid >> 1, wc = wid & 1;

  f32x4 acc[4][4] = {};

  const int srow = tid >> 2;
  const int scol = (tid & 3) * 8;
  const bf16* Ag = A + (size_t)(row0 + srow) * K + scol;
  const bf16* Bg = BT + (size_t)(col0 + srow) * K + scol;
  char* AsW = (char*)As + wid * 1024;
  char* BsW = (char*)Bs + wid * 1024;

  const int fr = lane & 15, fk = (lane >> 4) * 8;
  const bf16* aRd = As + (wr * 64 + fr) * 32 + fk;
  const bf16* bRd = Bs + (wc * 64 + fr) * 32 + fk;

  for (int k0 = 0; k0 < K; k0 += 32) {
    gload_lds16(Ag, AsW);
    gload_lds16(Ag + (size_t)64 * K, AsW + 4096);
    gload_lds16(Bg, BsW);
    gload_lds16(Bg + (size_t)64 * K, BsW + 4096);
    Ag += 32; Bg += 32;
    __syncthreads();
    short8v a[4], b[4];
#pragma unroll
    for (int m = 0; m < 4; ++m) a[m] = *(const short8v*)(aRd + m * 16 * 32);
#pragma unroll
    for (int n = 0; n < 4; ++n) b[n] = *(const short8v*)(bRd + n * 16 * 32);
#pragma unroll
    for (int m = 0; m < 4; ++m)
#pragma unroll
      for (int n = 0; n < 4; ++n)
        acc[m][n] = MFMA_16x16x32(a[m], b[n], acc[m][n]);
    __syncthreads();
  }

  const int crow = (lane >> 4) * 4, ccol = lane & 15;
  if (EPI == 0) {
    bf16* C = (bf16*)Cv;
#pragma unroll
    for (int m = 0; m < 4; ++m)
#pragma unroll
      for (int n = 0; n < 4; ++n) {
        bf16* Cp = C + (size_t)(row0 + wr * 64 + m * 16 + crow) * ldc
                     + col0 + wc * 64 + n * 16 + ccol;
#pragma unroll
        for (int r = 0; r < 4; ++r)
          Cp[(size_t)r * ldc] = __float2bfloat16(acc[m][n][r]);
      }
  } else if (EPI == 1) {
    bf16* C = (bf16*)Cv;
#pragma unroll
    for (int m = 0; m < 4; ++m)
#pragma unroll
      for (int n = 0; n < 4; ++n) {
        short4v pk;
#pragma unroll
        for (int r = 0; r < 4; ++r)
          pk[r] = (short)bf16bits(acc[m][n][r]);
        bf16* Cp = C + (size_t)(col0 + wc * 64 + n * 16 + ccol) * ldc
                     + row0 + wr * 64 + m * 16 + crow;
        *(short4v*)Cp = pk;
      }
  } else {
    float* C = (float*)Cv;
#pragma unroll
    for (int m = 0; m < 4; ++m)
#pragma unroll
      for (int n = 0; n < 4; ++n) {
        float* Cp = C + (size_t)(row0 + wr * 64 + m * 16 + crow) * ldc
                      + col0 + wc * 64 + n * 16 + ccol;
#pragma unroll
        for (int r = 0; r < 4; ++r)
          Cp[(size_t)r * ldc] = acc[m][n][r];
      }
  }
}

// XCD-contiguous remap (nwg % 8 == 0 for all our launches)
__device__ __forceinline__ int2 xcd_remap(int nx, int ny) {
  int flat = blockIdx.x + nx * blockIdx.y;
  int chunk = (nx * ny) >> 3;
  int role = (flat & 7) * chunk + (flat >> 3);
  return make_int2(role % nx, role / nx);
}

template<int EPI>
__global__ __launch_bounds__(256) void gemm_bt_kernel(
    const bf16* __restrict__ A, const bf16* __restrict__ BT, void* __restrict__ C,
    int K, int N)
{
  __shared__ bf16 As[128 * 32];
  __shared__ bf16 Bs[128 * 32];
  int2 bb = xcd_remap(gridDim.x, gridDim.y);
  gemm_tile_128<EPI>(A, BT, C, K, N, bb.y * 128, bb.x * 128, As, Bs);
}

// Fused Q-proj + KV-down (128-tile): N = 2048 (Wq) + 512 (Wdkv), K = 2048.
__global__ __launch_bounds__(256) void qkv_gemm_kernel(
    const bf16* __restrict__ xb, const bf16* __restrict__ Wqb,
    const bf16* __restrict__ Wdkvb, bf16* __restrict__ Qb, bf16* __restrict__ Ck)
{
  __shared__ bf16 As[128 * 32];
  __shared__ bf16 Bs[128 * 32];
  int2 bb = xcd_remap(20, 32);
  const int bx = bb.x, row0 = bb.y * 128;
  if (bx < 16)
    gemm_tile_128<0>(xb, Wqb, Qb, DMc, DMc, row0, bx * 128, As, Bs);
  else
    gemm_tile_128<0>(xb, Wdkvb, Ck, DMc, DLc, row0, (bx - 16) * 128, As, Bs);
}

// ---------------------------------------------------------------------------
// 8-phase 256x256 GEMM tile (T3+T4) -- r16-verified. Used ONLY where the
// grid covers all 256 CUs (up_gemm: 16x16 = 256 blocks).
// ---------------------------------------------------------------------------
#define GPHASE(bufv, KK, MH)                                                \
  do {                                                                      \
    const char* ap_ = aR + (bufv) * 32768 + (KK) * 8192 + (MH) * 4096;      \
    const char* bp_ = bR + (bufv) * 32768 + (KK) * 8192;                    \
    short8v af_[4], bf_[4];                                                 \
    _Pragma("unroll")                                                       \
    for (int m4 = 0; m4 < 4; ++m4)                                          \
      af_[m4] = *(const short8v*)(ap_ + m4 * 1024);                         \
    _Pragma("unroll")                                                       \
    for (int n = 0; n < 4; ++n)                                             \
      bf_[n] = *(const short8v*)(bp_ + n * 1024);                           \
    __builtin_amdgcn_s_setprio(1);                                          \
    _Pragma("unroll")                                                       \
    for (int m4 = 0; m4 < 4; ++m4)                                          \
      _Pragma("unroll")                                                     \
      for (int n = 0; n < 4; ++n)                                           \
        acc[(MH) * 4 + m4][n] =                                             \
            MFMA_16x16x32(af_[m4], bf_[n], acc[(MH) * 4 + m4][n]);          \
    __builtin_amdgcn_s_setprio(0);                                          \
  } while (0)

template<int EPI>
__device__ __forceinline__ void gemm_tile_256(
    const bf16* __restrict__ A, const bf16* __restrict__ BT, void* __restrict__ Cv,
    int K, int ldc, int row0, int col0, char* AsC, char* BsC)
{
  const int tid = threadIdx.x;
  const int lane = tid & 63, wid = tid >> 6;
  const int wm = wid >> 2, wn = wid & 3;
  const int fr = lane & 15, g = lane >> 4;

  f32x4 acc[8][4] = {};

  const int srow = tid >> 2;
  const int scolS = ((tid & 3) * 16) ^ (((srow >> 1) & 3) << 4);
  const bf16* sA = A + (size_t)(row0 + srow) * K + (scolS >> 1);
  const bf16* sB = BT + (size_t)(col0 + srow) * K + (scolS >> 1);
  char* AsW = AsC + wid * 1024;
  char* BsW = BsC + wid * 1024;

  auto ISSA = [&](int buf, int h, int kk, int kt) {
    gload_lds16(sA + (size_t)(h * 128) * K + kt * 64 + kk * 32,
                AsW + buf * 32768 + h * 16384 + kk * 8192);
  };
  auto ISSB = [&](int buf, int h, int kk, int kt) {
    gload_lds16(sB + (size_t)(h * 128) * K + kt * 64 + kk * 32,
                BsW + buf * 32768 + h * 16384 + kk * 8192);
  };

  const int rdLane = fr * 64 + ((g * 16) ^ (((fr >> 1) & 3) << 4));
  const char* aR = AsC + wm * 16384 + rdLane;
  const char* bR = BsC + (wn >> 1) * 16384 + (wn & 1) * 4096 + rdLane;

  ISSA(0, 0, 0, 0); ISSA(0, 1, 0, 0); ISSB(0, 0, 0, 0); ISSB(0, 1, 0, 0);
  ISSA(0, 0, 1, 0); ISSA(0, 1, 1, 0); ISSB(0, 0, 1, 0); ISSB(0, 1, 1, 0);

  const int KT = K >> 6;
  for (int kt = 0; kt < KT - 1; ++kt) {
    const int buf = kt & 1, nb = buf ^ 1;
    asm volatile("s_waitcnt vmcnt(4)" ::: "memory");
    __builtin_amdgcn_s_barrier();
    asm volatile("" ::: "memory");
    ISSA(nb, 0, 0, kt + 1); ISSA(nb, 1, 0, kt + 1);
    GPHASE(buf, 0, 0);
    ISSB(nb, 0, 0, kt + 1); ISSB(nb, 1, 0, kt + 1);
    GPHASE(buf, 0, 1);
    asm volatile("s_waitcnt vmcnt(4)" ::: "memory");
    __builtin_amdgcn_s_barrier();
    asm volatile("" ::: "memory");
    ISSA(nb, 0, 1, kt + 1); ISSA(nb, 1, 1, kt + 1);
    GPHASE(buf, 1, 0);
    ISSB(nb, 0, 1, kt + 1); ISSB(nb, 1, 1, kt + 1);
    GPHASE(buf, 1, 1);
  }
  {
    const int buf = (KT - 1) & 1;
    asm volatile("s_waitcnt vmcnt(4)" ::: "memory");
    __builtin_amdgcn_s_barrier();
    asm volatile("" ::: "memory");
    GPHASE(buf, 0, 0);
    GPHASE(buf, 0, 1);
    asm volatile("s_waitcnt vmcnt(0)" ::: "memory");
    __builtin_amdgcn_s_barrier();
    asm volatile("" ::: "memory");
    GPHASE(buf, 1, 0);
    GPHASE(buf, 1, 1);
  }

  const int crow = g * 4, ccol = fr;
  if (EPI == 0) {
    bf16* C = (bf16*)Cv;
#pragma unroll
    for (int m = 0; m < 8; ++m)
#pragma unroll
      for (int n = 0; n < 4; ++n) {
        bf16* Cp = C + (size_t)(row0 + wm * 128 + m * 16 + crow) * ldc
                     + col0 + wn * 64 + n * 16 + ccol;
#pragma unroll
        for (int r = 0; r < 4; ++r)
          Cp[(size_t)r * ldc] = __float2bfloat16(acc[m][n][r]);
      }
  } else if (EPI == 1) {
    bf16* C = (bf16*)Cv;
#pragma unroll
    for (int m = 0; m < 8; ++m)
#pragma unroll
      for (int n = 0; n < 4; ++n) {
        short4v pk;
#pragma unroll
        for (int r = 0; r < 4; ++r)
          pk[r] = (short)bf16bits(acc[m][n][r]);
        bf16* Cp = C + (size_t)(col0 + wn * 64 + n * 16 + ccol) * ldc
                     + row0 + wm * 128 + m * 16 + crow;
        *(short4v*)Cp = pk;
      }
  } else {
    float* C = (float*)Cv;
#pragma unroll
    for (int m = 0; m < 8; ++m)
#pragma unroll
      for (int n = 0; n < 4; ++n) {
        float* Cp = C + (size_t)(row0 + wm * 128 + m * 16 + crow) * ldc
                      + col0 + wn * 64 + n * 16 + ccol;
#pragma unroll
        for (int r = 0; r < 4; ++r)
          Cp[(size_t)r * ldc] = acc[m][n][r];
      }
  }
}

// Fused K-up + V-up (256-tile, 8-phase): grid (16,16) = 256 blocks = 1/CU.
__global__ __launch_bounds__(512, 2) void up_gemm_kernel(
    const bf16* __restrict__ Ck, const bf16* __restrict__ Wukb,
    const bf16* __restrict__ Wuvb, bf16* __restrict__ Kcat, bf16* __restrict__ VTcat)
{
  __shared__ char As[65536];
  __shared__ char Bs[65536];
  const int flat = blockIdx.x + 16 * blockIdx.y;
  const int role = (flat & 7) * 32 + (flat >> 3);
  const int bx = role & 15, by = role >> 4;
  if (bx < 8)
    gemm_tile_256<0>(Ck, Wukb, Kcat, DLc, DMc, by * 256, bx * 256, As, Bs);
  else
    gemm_tile_256<1>(Ck, Wuvb, VTcat, DLc, Bc * Sc, by * 256, (bx - 8) * 256, As, Bs);
}

// ---------------------------------------------------------------------------
// Flash attention (r15-verified): 32x32x16 swapped-operand MFMA, in-register
// softmax, cvt_pk/permlane32 P conversion; 4-wave blocks, 2 blocks/CU.
// ---------------------------------------------------------------------------
constexpr int KVB = 64;
constexpr int NTT = Sc / KVB;   // 32 tiles
constexpr int VSTR = Bc * Sc;   // 4096

__global__ __launch_bounds__(256, 2) void mla_attn_kernel(
    const bf16* __restrict__ Q, const bf16* __restrict__ Kcat,
    const bf16* __restrict__ VTcat, bf16* __restrict__ O)
{
  __shared__ bf16 Ks[2][KVB * 128];    // 16 KB each ([64][256B])
  __shared__ bf16 Vs[2][64 * 128];     // 16 KB each ([64][256B], d-pairs)

  const int tid = threadIdx.x, lane = tid & 63, wid = tid >> 6;  // wid 0..3
  const int l31 = lane & 31, hi = lane >> 5;

  const int flat = blockIdx.x + 16 * (blockIdx.y + 16 * blockIdx.z);
  const int role = (flat & 7) * 64 + (flat >> 3);
  const int qb = role & 15, h = (role >> 4) & 15, b = role >> 8;
  const int q0 = qb * 128 + wid * 32;

  const bf16* Qp = Q + (size_t)(b * Sc + q0 + l31) * DMc + h * DHc + hi * 8;
  short8v qf[8];
#pragma unroll
  for (int kk = 0; kk < 8; ++kk) qf[kk] = *(const short8v*)(Qp + kk * 16);

  const bf16* Kb = Kcat + (size_t)b * Sc * DMc + h * DHc;      // K[t][d], stride DMc
  const bf16* Vb = VTcat + (size_t)(h * DHc) * VSTR + b * Sc;  // VT[d][t], stride VSTR

  const int srow = wid * 4 + (lane >> 4);          // 0..15
  const int scolB = (lane & 15) * 16;
  const int swzK0 = ((srow & 7) << 4) ^ (((srow >> 3) & 1) << 6);
  const bf16* kpE = Kb + (size_t)srow * DMc + (((scolB ^ swzK0) & 255) >> 1);
  const bf16* kpO = Kb + (size_t)srow * DMc + ((((scolB ^ swzK0) ^ 128) & 255) >> 1);
  const int swzV0 = ((srow & 7) << 4) ^ (((srow >> 3) & 1) << 7);
  const int vcp = scolB ^ swzV0;
  const bf16* vp = Vb + (size_t)(2 * srow + (vcp >> 7)) * VSTR + ((vcp & 127) >> 1);

  auto STAGE = [&](int buf, int t0) {
    char* kd = (char*)(&Ks[buf][0]) + wid * 1024;
    gload_lds16(kpE + (size_t)t0 * DMc, kd);
    gload_lds16(kpO + (size_t)(t0 + 16) * DMc, kd + 4096);
    gload_lds16(kpE + (size_t)(t0 + 32) * DMc, kd + 8192);
    gload_lds16(kpO + (size_t)(t0 + 48) * DMc, kd + 12288);
    char* vd = (char*)(&Vs[buf][0]) + wid * 1024;
    const bf16* v0 = vp + t0;
    gload_lds16(v0, vd);
    gload_lds16(v0 + (size_t)32 * VSTR, vd + 4096);
    gload_lds16(v0 + (size_t)64 * VSTR, vd + 8192);
    gload_lds16(v0 + (size_t)96 * VSTR, vd + 12288);
  };

  const int swzR = ((l31 & 7) << 4) ^ (((l31 >> 3) & 1) << 6) ^ (((l31 >> 4) & 1) << 7);
  const int swzVR = (((l31 >> 1) & 7) << 4) ^ (((l31 >> 4) & 1) << 7);

  f32x16 oacc[4] = {};
  float m_r = -1e30f, l_r = 0.f, msc = 0.f;
  const float SCL2 = 0.12751650f;     // (1/sqrt(128)) * log2(e)
  const float THRraw = 47.0f;         // ~6 / SCL2 -> p bounded by 2^6

  STAGE(0, 0);
  int cur = 0;

  for (int it = 0; it < NTT; ++it) {
    asm volatile("s_waitcnt vmcnt(0)" ::: "memory");
    __builtin_amdgcn_s_barrier();
    asm volatile("" ::: "memory");
    if (it + 1 < NTT) STAGE(cur ^ 1, (it + 1) * KVB);
    asm volatile("" ::: "memory");

    f32x16 s0 = {}, s1 = {};
    const char* Kc = (const char*)(&Ks[cur][0]);
    __builtin_amdgcn_s_setprio(1);
#pragma unroll
    for (int kk = 0; kk < 8; ++kk) {
      const int cb = (kk * 32 + hi * 16) ^ swzR;
      short8v k0 = *(const short8v*)(Kc + l31 * 256 + cb);
      short8v k1 = *(const short8v*)(Kc + (32 + l31) * 256 + cb);
      s0 = MFMA_32x32x16(k0, qf[kk], s0);
      s1 = MFMA_32x32x16(k1, qf[kk], s1);
    }
    __builtin_amdgcn_s_setprio(0);

    float pm = s0[0];
#pragma unroll
    for (int i = 1; i < 16; ++i) pm = fmaxf(pm, s0[i]);
#pragma unroll
    for (int i = 0; i < 16; ++i) pm = fmaxf(pm, s1[i]);

    if (!__all(pm - m_r <= THRraw)) {
      float red = fmaxf(pm, __shfl_xor(pm, 32, 64));
      float mnew = fmaxf(m_r, red);
      float c = exp2f((m_r - mnew) * SCL2);
      m_r = mnew;
      msc = mnew * SCL2;
      l_r *= c;
#pragma unroll
      for (int db = 0; db < 4; ++db) oacc[db] *= c;
    }

    short8v pf[4];
#pragma unroll
    for (int tt = 0; tt < 2; ++tt) {
      const f32x16& s = tt ? s1 : s0;
#pragma unroll
      for (int half = 0; half < 2; ++half) {
        float e0 = exp2f(__builtin_fmaf(s[half * 8 + 0], SCL2, -msc));
        float e1 = exp2f(__builtin_fmaf(s[half * 8 + 1], SCL2, -msc));
        float e2 = exp2f(__builtin_fmaf(s[half * 8 + 2], SCL2, -msc));
        float e3 = exp2f(__builtin_fmaf(s[half * 8 + 3], SCL2, -msc));
        float e4 = exp2f(__builtin_fmaf(s[half * 8 + 4], SCL2, -msc));
        float e5 = exp2f(__builtin_fmaf(s[half * 8 + 5], SCL2, -msc));
        float e6 = exp2f(__builtin_fmaf(s[half * 8 + 6], SCL2, -msc));
        float e7 = exp2f(__builtin_fmaf(s[half * 8 + 7], SCL2, -msc));
        l_r += ((e0 + e1) + (e2 + e3)) + ((e4 + e5) + (e6 + e7));
        u32 cA, cB, cC, cD;
        asm("v_cvt_pk_bf16_f32 %0, %1, %2" : "=v"(cA) : "v"(e0), "v"(e1));
        asm("v_cvt_pk_bf16_f32 %0, %1, %2" : "=v"(cB) : "v"(e2), "v"(e3));
        asm("v_cvt_pk_bf16_f32 %0, %1, %2" : "=v"(cC) : "v"(e4), "v"(e5));
        asm("v_cvt_pk_bf16_f32 %0, %1, %2" : "=v"(cD) : "v"(e6), "v"(e7));
        asm volatile("v_permlane32_swap_b32 %0, %1" : "+v"(cA), "+v"(cC));
        asm volatile("v_permlane32_swap_b32 %0, %1" : "+v"(cB), "+v"(cD));
        uint4v w;
        w[0] = cA; w[1] = cB; w[2] = cC; w[3] = cD;
        pf[tt * 2 + half] = __builtin_bit_cast(short8v, w);
      }
    }

    const char* Vc = (const char*)(&Vs[cur][0]);
    __builtin_amdgcn_s_setprio(1);
#pragma unroll
    for (int db = 0; db < 4; ++db) {
      const int vrow = (db * 16 + (l31 >> 1)) * 256;
#pragma unroll
      for (int ts = 0; ts < 4; ++ts) {
        const int cb = ((l31 & 1) * 128 + ts * 32 + hi * 16) ^ swzVR;
        short8v vf = *(const short8v*)(Vc + vrow + cb);
        oacc[db] = MFMA_32x32x16(vf, pf[ts], oacc[db]);
      }
    }
    __builtin_amdgcn_s_setprio(0);

    cur ^= 1;
  }

  float l = l_r + __shfl_xor(l_r, 32, 64);
  float inv = 1.f / l;
  bf16* Op = O + (size_t)(b * Sc + q0 + l31) * DMc + h * DHc + hi * 4;
#pragma unroll
  for (int db = 0; db < 4; ++db) {
#pragma unroll
    for (int rq = 0; rq < 4; ++rq) {
      short4v pk;
#pragma unroll
      for (int r = 0; r < 4; ++r)
        pk[r] = (short)bf16bits(oacc[db][rq * 4 + r] * inv);
      *(short4v*)(Op + db * 32 + rq * 8) = pk;
    }
  }
}

// ---------------------------------------------------------------------------
extern "C" void kernel_launch(void* const* d_in, const int* in_sizes, int n_in,
                              void* d_out, int out_size, void* d_ws, size_t ws_size,
                              hipStream_t stream)
{
  const float* x    = (const float*)d_in[0];
  const float* Wq   = (const float*)d_in[1];
  const float* Wdkv = (const float*)d_in[2];
  const float* Wuk  = (const float*)d_in[3];
  const float* Wuv  = (const float*)d_in[4];
  const float* Wo   = (const float*)d_in[5];
  float* out = (float*)d_out;

  char* ws = (char*)d_ws;
  bf16* Qb    = (bf16*)(ws + 0);              // 16 MB
  bf16* Kcat  = (bf16*)(ws + 16777216);       // 16 MB  (B*S, H*DH)
  bf16* VTcat = (bf16*)(ws + 33554432);       // 16 MB  (H*DH, B*S)
  bf16* xb    = (bf16*)(ws + 50331648);       // 16 MB (dead after qkv gemm)
  bf16* AO    = (bf16*)(ws + 50331648);       // overlay: attn output
  bf16* Ck    = (bf16*)(ws + 67108864);       //  4 MB
  bf16* Wqb   = (bf16*)(ws + 71303168);       //  8 MB
  bf16* Wdkvb = (bf16*)(ws + 79691776);       //  2 MB
  bf16* Wukb  = (bf16*)(ws + 81788928);       //  2 MB
  bf16* Wuvb  = (bf16*)(ws + 83886080);       //  2 MB
  bf16* Wob   = (bf16*)(ws + 85983232);       //  8 MB

  dim3 blk(256, 1, 1);

  CvtArgs ca;
  ca.src[0] = x;    ca.dst[0] = xb;
  ca.src[1] = Wq;   ca.dst[1] = Wqb;
  ca.src[2] = Wdkv; ca.dst[2] = Wdkvb;
  ca.src[3] = Wuk;  ca.dst[3] = Wukb;
  ca.src[4] = Wuv;  ca.dst[4] = Wuvb;
  ca.src[5] = Wo;   ca.dst[5] = Wob;
  unsigned int n4[6] = { (unsigned)(Bc * Sc * DMc / 4), (unsigned)(DMc * DMc / 4),
                         (unsigned)(DLc * DMc / 4),     (unsigned)(Hc * DHc * DLc / 4),
                         (unsigned)(Hc * DHc * DLc / 4),(unsigned)(DMc * DMc / 4) };
  unsigned int acc = 0;
  for (int i = 0; i < 6; ++i) { ca.cum[i] = acc; acc += n4[i]; }
  ca.total4 = acc;
  cvt_all_kernel<<<2048, blk, 0, stream>>>(ca);

  // Q = x@Wq^T and Ckv = x@Wdkv^T (128-tile, full grid)
  qkv_gemm_kernel<<<dim3(20, 32), blk, 0, stream>>>(xb, Wqb, Wdkvb, Qb, Ck);

  // K/V up-projections (256-tile 8-phase, grid = 256 = 1/CU)
  up_gemm_kernel<<<dim3(16, 16), dim3(512, 1, 1), 0, stream>>>(Ck, Wukb, Wuvb, Kcat, VTcat);

  // attention: 4-wave blocks, 2 blocks/CU
  mla_attn_kernel<<<dim3(Sc / 128, Hc, Bc), dim3(256, 1, 1), 0, stream>>>(
      Qb, Kcat, VTcat, AO);

  // out = AO @ Wo^T (fp32 out, 128-tile, full grid)
  gemm_bt_kernel<2><<<dim3(16, 32), blk, 0, stream>>>(AO, Wob, out, DMc, DMc);
}